// Round 15
// baseline (389.094 us; speedup 1.0000x reference)
//
#include <hip/hip_runtime.h>

// MalleConv: all f32. Head feature maps stored PADDED (zero halo) so conv3x3
// needs no bounds checks and no LDS staging.
// feat0p/tmpAp: (4,32,130,136) stride 136, interior at [row+1][col+4], CS=17680
// feat1p/tmpBp: (4,32,66,72)   stride 72,  interior at [row+1][col+4], CS=4752

#define BATCH 4
#define NCH 32
#define CS128 17680
#define SP128 136
#define CS64 4752
#define SP64 72

__device__ __forceinline__ float fast_tanh(float s) {
  float e = __expf(2.f * s);
  return fmaf(-2.f, __builtin_amdgcn_rcpf(e + 1.f), 1.f);
}

// ---- zero padded head buffers (5,742,592 floats = 1,435,648 float4)
__global__ void zero_kernel(float* __restrict__ p) {
  int i = blockIdx.x * 256 + threadIdx.x;  // 5608*256 = 1,435,648
  *reinterpret_cast<float4*>(p + (size_t)i * 4) = make_float4(0.f, 0.f, 0.f, 0.f);
}

// ---- prep: pa_w (8,co,ci,9)->(8,ci,9,co); exp_w (320,32)->(32,320); pw_w (o,c)->(c,o)
__global__ void prep_kernel(const float* __restrict__ pa_w, const float* __restrict__ exp_w,
                            const float* __restrict__ pw_w, float* __restrict__ wt,
                            float* __restrict__ ewt, float* __restrict__ pwt) {
  int i = blockIdx.x * 256 + threadIdx.x;
  if (i < 73728) {
    int tap = i % 9; int t = i / 9;
    int ci = t & 31; t >>= 5;
    int co = t & 31; int layer = t >> 5;
    wt[((layer * 32 + ci) * 9 + tap) * 32 + co] = pa_w[i];
  } else if (i < 83968) {
    int j = i - 73728; int ci = j & 31; int o = j >> 5;
    ewt[ci * 320 + o] = exp_w[j];
  } else if (i < 84992) {
    int j = i - 83968; int c = j & 31; int o = j >> 5;
    pwt[c * 32 + o] = pw_w[j];
  }
}

// ---- avgpool k=4: x(B,C,512,512) -> feat0p interior
__global__ void avgpool4_kernel(const float* __restrict__ x, float* __restrict__ outp) {
  int idx = blockIdx.x * 256 + threadIdx.x;
  if (idx >= BATCH * NCH * 128 * 128) return;
  int ow = idx & 127; int t = idx >> 7; int oh = t & 127; int bc = t >> 7;
  const float* src = x + ((size_t)(bc * 512 + oh * 4)) * 512 + ow * 4;
  float s = 0.f;
#pragma unroll
  for (int r = 0; r < 4; r++) {
    float4 v = *reinterpret_cast<const float4*>(src + (size_t)r * 512);
    s += v.x + v.y + v.z + v.w;
  }
  outp[(size_t)bc * CS128 + (size_t)(oh + 1) * SP128 + ow + 4] = s * 0.0625f;
}

// ---- avgpool k=2: feat0p interior -> feat1p interior
__global__ void avgpool2_kernel(const float* __restrict__ inp, float* __restrict__ outp) {
  int idx = blockIdx.x * 256 + threadIdx.x;
  if (idx >= BATCH * NCH * 64 * 64) return;
  int ow = idx & 63; int t = idx >> 6; int oh = t & 63; int bc = t >> 6;
  const float* sp = inp + (size_t)bc * CS128 + (size_t)(2 * oh + 1) * SP128 + 2 * ow + 4;
  float2 a = *reinterpret_cast<const float2*>(sp);
  float2 b = *reinterpret_cast<const float2*>(sp + SP128);
  outp[(size_t)bc * CS64 + (size_t)(oh + 1) * SP64 + ow + 4] = (a.x + a.y + b.x + b.y) * 0.25f;
}

// ---- conv3x3 direct (padded in/out, no LDS, no bounds checks).
template <int HS, int SP, int CS, int NCO, bool RELU, bool RES>
__global__ __launch_bounds__(256) void conv3x3d_kernel(
    const float* __restrict__ in, const float* __restrict__ wt,
    const float* __restrict__ bias, const float* __restrict__ res,
    float* __restrict__ out) {
  constexpr int TILES = HS / 16;
  constexpr int GROUPS = 32 / NCO;
  int blk = blockIdx.x;
  int g = blk % GROUPS; int rest = blk / GROUPS;
  int b = rest / (TILES * TILES); int t = rest % (TILES * TILES);
  int ty = t / TILES, tx = t % TILES;
  int og = g * NCO;
  int px = threadIdx.x & 15, py = threadIdx.x >> 4;
  int gy = ty * 16 + py, gx = tx * 16 + px;
  size_t pix = (size_t)(gy + 1) * SP + gx + 4;
  const float* inb = in + (size_t)b * 32 * CS + pix;

  float acc[NCO];
#pragma unroll
  for (int o = 0; o < NCO; o++) acc[o] = bias[og + o];

#pragma unroll 2
  for (int ci = 0; ci < 32; ci++) {
    const float* p = inb + (size_t)ci * CS;
    float v[9];
    v[0] = p[-SP - 1]; v[1] = p[-SP]; v[2] = p[-SP + 1];
    v[3] = p[-1];      v[4] = p[0];   v[5] = p[1];
    v[6] = p[SP - 1];  v[7] = p[SP];  v[8] = p[SP + 1];
    const float* wr = wt + ci * 288 + og;
#pragma unroll
    for (int tap = 0; tap < 9; tap++) {
      const float* wrow = wr + tap * 32;
#pragma unroll
      for (int o = 0; o < NCO; o++)
        acc[o] = fmaf(v[tap], wrow[o], acc[o]);
    }
  }

  float* ob = out + (size_t)b * 32 * CS + (size_t)og * CS + pix;
  const float* rb = RES ? (res + (size_t)b * 32 * CS + (size_t)og * CS + pix) : nullptr;
#pragma unroll
  for (int o = 0; o < NCO; o++) {
    float r2 = acc[o];
    if (RELU) r2 = r2 > 0.f ? r2 : 0.01f * r2;
    if (RES) r2 += rb[(size_t)o * CS];
    ob[(size_t)o * CS] = r2;
  }
}

// ---- expander 1x1 (32->320) + fast tanh, padded feat1p input.
__global__ __launch_bounds__(256) void expander_kernel(
    const float* __restrict__ feat, const float* __restrict__ ewt,
    const float* __restrict__ eb, float* __restrict__ wmap) {
  int idx = blockIdx.x * 256 + threadIdx.x;  // 1,310,720
  int wq = idx & 15; int t = idx >> 4;
  int o = t % 320; int rest = t / 320;
  int hb = rest & 63; int b = rest >> 6;
  const float* fp = feat + (size_t)b * 32 * CS64 + (size_t)(hb + 1) * SP64 + 4 + wq * 4;
  float s0 = eb[o];
  float s1 = s0, s2 = s0, s3 = s0;
#pragma unroll 8
  for (int ci = 0; ci < 32; ci++) {
    float4 f = *reinterpret_cast<const float4*>(fp + (size_t)ci * CS64);
    float wv = ewt[ci * 320 + o];
    s0 = fmaf(f.x, wv, s0); s1 = fmaf(f.y, wv, s1);
    s2 = fmaf(f.z, wv, s2); s3 = fmaf(f.w, wv, s3);
  }
  float4 r;
  r.x = fast_tanh(s0); r.y = fast_tanh(s1);
  r.z = fast_tanh(s2); r.w = fast_tanh(s3);
  *reinterpret_cast<float4*>(wmap + (size_t)((b * 64 + hb) * 320 + o) * 64 + wq * 4) = r;
}

// ---- fused flying conv + final 1x1, v6: 256 threads, 2 px/thread,
// division-free staging (fixed per-thread channel/lane map, additive addresses).
// x taps read as aligned b64 pairs (2-lane/bank = conflict-free).
__global__ __launch_bounds__(256) void fused_fly_pw_kernel(
    const float* __restrict__ x, const float* __restrict__ wmap,
    const float* __restrict__ pwt, const float* __restrict__ pw_b,
    float* __restrict__ out) {
  __shared__ float s_w[8][322];
  __shared__ float s_x[8][10][68];
  int blk = blockIdx.x;  // ((b*64+hb)*8 + wtile)
  int wtile = blk & 7; int t = blk >> 3; int hb = t & 63; int b = t >> 6;
  int tid = threadIdx.x;

  const float* wsrc = wmap + (size_t)(b * 64 + hb) * 320 * 64 + wtile * 8;
#pragma unroll
  for (int j = 0; j < 10; j++) {
    int idx = j * 256 + tid;
    int tap = idx >> 3, wb8 = idx & 7;
    s_w[wb8][tap] = wsrc[(size_t)tap * 64 + wb8];
  }

  int p = tid & 31, row = tid >> 5;
  int h = hb * 8 + row;
  int w0 = wtile * 64 + 2 * p;
  int wbl = p >> 2;
  int h0 = hb * 8;
  int gc0 = wtile * 64 - 1;  // global col of s_x col 0
  const float* xb = x + (size_t)b * 32 * 262144;

  // staging map: thread -> (sch, lane); cols lane, lane+32, (lane<2: lane+64)
  int sch = tid >> 5, lane = tid & 31;
  int gxa = gc0 + lane, gxb = gc0 + lane + 32, gxc = gc0 + lane + 64;
  bool oka = (gxa >= 0);             // gxa < 512 always (max 7*64-1+31 = 478)
  bool okc = (lane < 2) && (gxc < 512);

  float2 acc[32];
#pragma unroll
  for (int o = 0; o < 32; o++) {
    float bv = pw_b[o];
    acc[o].x = bv; acc[o].y = bv;
  }

  for (int g = 0; g < 4; g++) {
    __syncthreads();  // protect s_x of previous group (and s_w on g=0)
    {
      const float* xc = xb + (size_t)(g * 8 + sch) * 262144;
      float* sxc = &s_x[sch][0][0];
#pragma unroll
      for (int rr = 0; rr < 10; rr++) {
        int gy = h0 - 1 + rr;
        bool oky = (gy >= 0) && (gy < 512);  // block-uniform
        const float* rp = xc + (size_t)gy * 512;
        sxc[rr * 68 + lane]      = (oky && oka) ? rp[gxa] : 0.f;
        sxc[rr * 68 + lane + 32] = oky ? rp[gxb] : 0.f;
        if (lane < 2)
          sxc[rr * 68 + lane + 64] = (oky && okc) ? rp[gxc] : 0.f;
      }
    }
    __syncthreads();  // s_x ready

#pragma unroll
    for (int c8 = 0; c8 < 8; c8++) {
      int c = g * 8 + c8;
      const float2* wr2 = reinterpret_cast<const float2*>(&s_w[wbl][c * 10]);
      float2 w01 = wr2[0], w23 = wr2[1], w45 = wr2[2], w67 = wr2[3], w89 = wr2[4];
      float wv[9];
      wv[0] = w01.x; wv[1] = w01.y; wv[2] = w23.x;
      wv[3] = w23.y; wv[4] = w45.x; wv[5] = w45.y;
      wv[6] = w67.x; wv[7] = w67.y; wv[8] = w89.x;
      float fly0 = w89.y, fly1 = w89.y;  // bias tap

#pragma unroll
      for (int di = 0; di < 3; di++) {
        const float2* rp = reinterpret_cast<const float2*>(&s_x[c8][row + di][2 * p]);
        float2 a = rp[0], bb = rp[1];
        // a.x = x[w0-1], a.y = x[w0], bb.x = x[w0+1], bb.y = x[w0+2]
        float wa = wv[di * 3 + 0], wb_ = wv[di * 3 + 1], wc = wv[di * 3 + 2];
        fly0 = fmaf(a.x, wa, fly0); fly0 = fmaf(a.y, wb_, fly0); fly0 = fmaf(bb.x, wc, fly0);
        fly1 = fmaf(a.y, wa, fly1); fly1 = fmaf(bb.x, wb_, fly1); fly1 = fmaf(bb.y, wc, fly1);
      }
      const float* prow = pwt + c * 32;
#pragma unroll
      for (int o = 0; o < 32; o++) {
        float pw = prow[o];
        acc[o].x = fmaf(fly0, pw, acc[o].x);
        acc[o].y = fmaf(fly1, pw, acc[o].y);
      }
    }
  }
  float* ob = out + (size_t)b * 32 * 262144 + (size_t)h * 512 + w0;
#pragma unroll
  for (int o = 0; o < 32; o++)
    *reinterpret_cast<float2*>(ob + (size_t)o * 262144) = acc[o];
}

extern "C" void kernel_launch(void* const* d_in, const int* in_sizes, int n_in,
                              void* d_out, int out_size, void* d_ws, size_t ws_size,
                              hipStream_t stream) {
  const float* x     = (const float*)d_in[0];
  const float* pa_w  = (const float*)d_in[1];
  const float* pa_b  = (const float*)d_in[2];
  const float* exp_w = (const float*)d_in[3];
  const float* exp_b = (const float*)d_in[4];
  const float* pw_w  = (const float*)d_in[5];
  const float* pw_b  = (const float*)d_in[6];
  float* out = (float*)d_out;
  float* ws  = (float*)d_ws;

  float* feat0p = ws;                    // 4*32*130*136 = 2,263,040
  float* tmpAp  = feat0p + 2263040;      // 2,263,040
  float* feat1p = tmpAp + 2263040;       // 4*32*66*72 = 608,256
  float* wmap   = feat1p + 608256;       // 5,242,880
  float* tmpBp  = wmap;                  // aliases wmap (dead before expander writes)
  float* wt     = wmap + 5242880;        // 73,728
  float* ewt    = wt + 73728;            // 10,240
  float* pwt    = ewt + 10240;           // 1,024

  hipLaunchKernelGGL(zero_kernel, dim3(5608), dim3(256), 0, stream, ws);
  hipLaunchKernelGGL(prep_kernel, dim3(332), dim3(256), 0, stream, pa_w, exp_w, pw_w, wt, ewt, pwt);
  hipLaunchKernelGGL(avgpool4_kernel, dim3(8192), dim3(256), 0, stream, x, feat0p);

  // predictors @128: NCO=4 -> 2048 blocks (8/CU, 32 waves/CU)
  for (int i = 0; i < 2; i++) {
    const float* w1 = wt + (size_t)(i * 2 + 0) * 9216;
    const float* b1 = pa_b + (i * 2 + 0) * 32;
    const float* w2 = wt + (size_t)(i * 2 + 1) * 9216;
    const float* b2 = pa_b + (i * 2 + 1) * 32;
    hipLaunchKernelGGL((conv3x3d_kernel<128, SP128, CS128, 4, true, false>),
                       dim3(2048), dim3(256), 0, stream, feat0p, w1, b1, nullptr, tmpAp);
    hipLaunchKernelGGL((conv3x3d_kernel<128, SP128, CS128, 4, false, true>),
                       dim3(2048), dim3(256), 0, stream, tmpAp, w2, b2, feat0p, feat0p);
  }

  hipLaunchKernelGGL(avgpool2_kernel, dim3(2048), dim3(256), 0, stream, feat0p, feat1p);

  // predictors @64: NCO=2 -> 1024 blocks
  for (int i = 2; i < 4; i++) {
    const float* w1 = wt + (size_t)(i * 2 + 0) * 9216;
    const float* b1 = pa_b + (i * 2 + 0) * 32;
    const float* w2 = wt + (size_t)(i * 2 + 1) * 9216;
    const float* b2 = pa_b + (i * 2 + 1) * 32;
    hipLaunchKernelGGL((conv3x3d_kernel<64, SP64, CS64, 2, true, false>),
                       dim3(1024), dim3(256), 0, stream, feat1p, w1, b1, nullptr, tmpBp);
    hipLaunchKernelGGL((conv3x3d_kernel<64, SP64, CS64, 2, false, true>),
                       dim3(1024), dim3(256), 0, stream, tmpBp, w2, b2, feat1p, feat1p);
  }

  hipLaunchKernelGGL(expander_kernel, dim3(5120), dim3(256), 0, stream, feat1p, ewt, exp_b, wmap);

  hipLaunchKernelGGL(fused_fly_pw_kernel, dim3(2048), dim3(256), 0, stream,
                     x, wmap, pwt, pw_b, out);
}

// Round 16
// 330.422 us; speedup vs baseline: 1.1776x; 1.1776x over previous
//
#include <hip/hip_runtime.h>

// MalleConv: all f32. Head feature maps stored PADDED (zero halo).
// feat0p/tmpAp: (4,32,130,136) stride 136, interior [row+1][col+4], CS=17680
// feat1p/tmpBp: (4,32,66,72)   stride 72,  interior [row+1][col+4], CS=4752

#define BATCH 4
#define NCH 32
#define CS128 17680
#define SP128 136
#define CS64 4752
#define SP64 72

__device__ __forceinline__ float fast_tanh(float s) {
  float e = __expf(2.f * s);
  return fmaf(-2.f, __builtin_amdgcn_rcpf(e + 1.f), 1.f);
}

// ---- zero padded head buffers
__global__ void zero_kernel(float* __restrict__ p) {
  int i = blockIdx.x * 256 + threadIdx.x;  // 5608*256 = 1,435,648
  *reinterpret_cast<float4*>(p + (size_t)i * 4) = make_float4(0.f, 0.f, 0.f, 0.f);
}

// ---- prep: pa_w (8,co,ci,9)->(8,ci,9,co); exp_w (320,32)->(32,320); pw_w (o,c)->(c,o)
__global__ void prep_kernel(const float* __restrict__ pa_w, const float* __restrict__ exp_w,
                            const float* __restrict__ pw_w, float* __restrict__ wt,
                            float* __restrict__ ewt, float* __restrict__ pwt) {
  int i = blockIdx.x * 256 + threadIdx.x;
  if (i < 73728) {
    int tap = i % 9; int t = i / 9;
    int ci = t & 31; t >>= 5;
    int co = t & 31; int layer = t >> 5;
    wt[((layer * 32 + ci) * 9 + tap) * 32 + co] = pa_w[i];
  } else if (i < 83968) {
    int j = i - 73728; int ci = j & 31; int o = j >> 5;
    ewt[ci * 320 + o] = exp_w[j];
  } else if (i < 84992) {
    int j = i - 83968; int c = j & 31; int o = j >> 5;
    pwt[c * 32 + o] = pw_w[j];
  }
}

// ---- avgpool k=4: x(B,C,512,512) -> feat0p interior
__global__ void avgpool4_kernel(const float* __restrict__ x, float* __restrict__ outp) {
  int idx = blockIdx.x * 256 + threadIdx.x;
  if (idx >= BATCH * NCH * 128 * 128) return;
  int ow = idx & 127; int t = idx >> 7; int oh = t & 127; int bc = t >> 7;
  const float* src = x + ((size_t)(bc * 512 + oh * 4)) * 512 + ow * 4;
  float s = 0.f;
#pragma unroll
  for (int r = 0; r < 4; r++) {
    float4 v = *reinterpret_cast<const float4*>(src + (size_t)r * 512);
    s += v.x + v.y + v.z + v.w;
  }
  outp[(size_t)bc * CS128 + (size_t)(oh + 1) * SP128 + ow + 4] = s * 0.0625f;
}

// ---- avgpool k=2: feat0p interior -> feat1p interior
__global__ void avgpool2_kernel(const float* __restrict__ inp, float* __restrict__ outp) {
  int idx = blockIdx.x * 256 + threadIdx.x;
  if (idx >= BATCH * NCH * 64 * 64) return;
  int ow = idx & 63; int t = idx >> 6; int oh = t & 63; int bc = t >> 6;
  const float* sp = inp + (size_t)bc * CS128 + (size_t)(2 * oh + 1) * SP128 + 2 * ow + 4;
  float2 a = *reinterpret_cast<const float2*>(sp);
  float2 b = *reinterpret_cast<const float2*>(sp + SP128);
  outp[(size_t)bc * CS64 + (size_t)(oh + 1) * SP64 + ow + 4] = (a.x + a.y + b.x + b.y) * 0.25f;
}

// ---- conv3x3 direct, 2 VERTICAL px/thread (12 loads feed 72 FMAs per ci).
// Tile: 16 cols x 32 rows; 256 threads = 16 x 16 row-pairs.
template <int HS, int SP, int CS, int NCO, bool RELU, bool RES>
__global__ __launch_bounds__(256) void conv3x3v_kernel(
    const float* __restrict__ in, const float* __restrict__ wt,
    const float* __restrict__ bias, const float* __restrict__ res,
    float* __restrict__ out) {
  constexpr int TX = HS / 16;
  constexpr int TY = HS / 32;
  constexpr int GROUPS = 32 / NCO;
  int blk = blockIdx.x;
  int g = blk % GROUPS; int rest = blk / GROUPS;
  int b = rest / (TX * TY); int t = rest % (TX * TY);
  int ty = t / TX, tx = t % TX;
  int og = g * NCO;
  int px = threadIdx.x & 15, py = threadIdx.x >> 4;
  int gy = ty * 32 + py * 2, gx = tx * 16 + px;
  size_t pix = (size_t)(gy + 1) * SP + gx + 4;
  const float* inb = in + (size_t)b * 32 * CS + pix;

  float acc0[NCO], acc1[NCO];
#pragma unroll
  for (int o = 0; o < NCO; o++) { acc0[o] = bias[og + o]; acc1[o] = acc0[o]; }

#pragma unroll 2
  for (int ci = 0; ci < 32; ci++) {
    const float* p = inb + (size_t)ci * CS;
    float v[12];
    v[0] = p[-SP - 1];    v[1] = p[-SP];     v[2] = p[-SP + 1];
    v[3] = p[-1];         v[4] = p[0];       v[5] = p[1];
    v[6] = p[SP - 1];     v[7] = p[SP];      v[8] = p[SP + 1];
    v[9] = p[2 * SP - 1]; v[10] = p[2 * SP]; v[11] = p[2 * SP + 1];
    const float* wr = wt + ci * 288 + og;
#pragma unroll
    for (int tap = 0; tap < 9; tap++) {
      const float* wrow = wr + tap * 32;
#pragma unroll
      for (int o = 0; o < NCO; o++) {
        acc0[o] = fmaf(v[tap], wrow[o], acc0[o]);
        acc1[o] = fmaf(v[tap + 3], wrow[o], acc1[o]);
      }
    }
  }

  float* ob = out + (size_t)b * 32 * CS + (size_t)og * CS + pix;
  const float* rb = RES ? (res + (size_t)b * 32 * CS + (size_t)og * CS + pix) : nullptr;
#pragma unroll
  for (int o = 0; o < NCO; o++) {
    float r0 = acc0[o], r1 = acc1[o];
    if (RELU) { r0 = r0 > 0.f ? r0 : 0.01f * r0; r1 = r1 > 0.f ? r1 : 0.01f * r1; }
    if (RES) { r0 += rb[(size_t)o * CS]; r1 += rb[(size_t)o * CS + SP]; }
    ob[(size_t)o * CS] = r0;
    ob[(size_t)o * CS + SP] = r1;
  }
}

// ---- conv3x3 direct 1px (kept for @64 layers).
template <int HS, int SP, int CS, int NCO, bool RELU, bool RES>
__global__ __launch_bounds__(256) void conv3x3d_kernel(
    const float* __restrict__ in, const float* __restrict__ wt,
    const float* __restrict__ bias, const float* __restrict__ res,
    float* __restrict__ out) {
  constexpr int TILES = HS / 16;
  constexpr int GROUPS = 32 / NCO;
  int blk = blockIdx.x;
  int g = blk % GROUPS; int rest = blk / GROUPS;
  int b = rest / (TILES * TILES); int t = rest % (TILES * TILES);
  int ty = t / TILES, tx = t % TILES;
  int og = g * NCO;
  int px = threadIdx.x & 15, py = threadIdx.x >> 4;
  int gy = ty * 16 + py, gx = tx * 16 + px;
  size_t pix = (size_t)(gy + 1) * SP + gx + 4;
  const float* inb = in + (size_t)b * 32 * CS + pix;

  float acc[NCO];
#pragma unroll
  for (int o = 0; o < NCO; o++) acc[o] = bias[og + o];

#pragma unroll 2
  for (int ci = 0; ci < 32; ci++) {
    const float* p = inb + (size_t)ci * CS;
    float v[9];
    v[0] = p[-SP - 1]; v[1] = p[-SP]; v[2] = p[-SP + 1];
    v[3] = p[-1];      v[4] = p[0];   v[5] = p[1];
    v[6] = p[SP - 1];  v[7] = p[SP];  v[8] = p[SP + 1];
    const float* wr = wt + ci * 288 + og;
#pragma unroll
    for (int tap = 0; tap < 9; tap++) {
      const float* wrow = wr + tap * 32;
#pragma unroll
      for (int o = 0; o < NCO; o++)
        acc[o] = fmaf(v[tap], wrow[o], acc[o]);
    }
  }

  float* ob = out + (size_t)b * 32 * CS + (size_t)og * CS + pix;
  const float* rb = RES ? (res + (size_t)b * 32 * CS + (size_t)og * CS + pix) : nullptr;
#pragma unroll
  for (int o = 0; o < NCO; o++) {
    float r2 = acc[o];
    if (RELU) r2 = r2 > 0.f ? r2 : 0.01f * r2;
    if (RES) r2 += rb[(size_t)o * CS];
    ob[(size_t)o * CS] = r2;
  }
}

// ---- expander 1x1 (32->320) + fast tanh, padded feat1p input.
__global__ __launch_bounds__(256) void expander_kernel(
    const float* __restrict__ feat, const float* __restrict__ ewt,
    const float* __restrict__ eb, float* __restrict__ wmap) {
  int idx = blockIdx.x * 256 + threadIdx.x;  // 1,310,720
  int wq = idx & 15; int t = idx >> 4;
  int o = t % 320; int rest = t / 320;
  int hb = rest & 63; int b = rest >> 6;
  const float* fp = feat + (size_t)b * 32 * CS64 + (size_t)(hb + 1) * SP64 + 4 + wq * 4;
  float s0 = eb[o];
  float s1 = s0, s2 = s0, s3 = s0;
#pragma unroll 8
  for (int ci = 0; ci < 32; ci++) {
    float4 f = *reinterpret_cast<const float4*>(fp + (size_t)ci * CS64);
    float wv = ewt[ci * 320 + o];
    s0 = fmaf(f.x, wv, s0); s1 = fmaf(f.y, wv, s1);
    s2 = fmaf(f.z, wv, s2); s3 = fmaf(f.w, wv, s3);
  }
  float4 r;
  r.x = fast_tanh(s0); r.y = fast_tanh(s1);
  r.z = fast_tanh(s2); r.w = fast_tanh(s3);
  *reinterpret_cast<float4*>(wmap + (size_t)((b * 64 + hb) * 320 + o) * 64 + wq * 4) = r;
}

// ---- fused flying conv + final 1x1, v7: x read DIRECT from global (L1-cached,
// guarded aligned loads), w from LDS (b64 broadcast). 2 px/thread, ONE barrier.
__global__ __launch_bounds__(256) void fused_fly_pw_kernel(
    const float* __restrict__ x, const float* __restrict__ wmap,
    const float* __restrict__ pwt, const float* __restrict__ pw_b,
    float* __restrict__ out) {
  __shared__ float s_w[8][322];
  int blk = blockIdx.x;  // ((b*64+hb)*8 + wtile)
  int wtile = blk & 7; int t = blk >> 3; int hb = t & 63; int b = t >> 6;
  int tid = threadIdx.x;

  const float* wsrc = wmap + (size_t)(b * 64 + hb) * 320 * 64 + wtile * 8;
#pragma unroll
  for (int j = 0; j < 10; j++) {
    int idx = j * 256 + tid;
    int tap = idx >> 3, wb8 = idx & 7;
    s_w[wb8][tap] = wsrc[(size_t)tap * 64 + wb8];
  }
  __syncthreads();

  int p = tid & 31, row = tid >> 5;
  int h = hb * 8 + row;
  int w0 = wtile * 64 + 2 * p;
  int wbl = p >> 2;
  const float* xb = x + (size_t)b * 32 * 262144;
  bool wl_ok = (w0 > 0), wr_ok = (w0 < 510);

  float2 acc[32];
#pragma unroll
  for (int o = 0; o < 32; o++) {
    float bv = pw_b[o];
    acc[o].x = bv; acc[o].y = bv;
  }

  for (int c = 0; c < 32; c++) {
    const float2* w2p = reinterpret_cast<const float2*>(&s_w[wbl][c * 10]);
    float2 w01 = w2p[0], w23 = w2p[1], w45 = w2p[2], w67 = w2p[3], w89 = w2p[4];
    float wv[9];
    wv[0] = w01.x; wv[1] = w01.y; wv[2] = w23.x;
    wv[3] = w23.y; wv[4] = w45.x; wv[5] = w45.y;
    wv[6] = w67.x; wv[7] = w67.y; wv[8] = w89.x;
    float fly0 = w89.y, fly1 = w89.y;  // bias tap

    const float* xc = xb + (size_t)c * 262144;
#pragma unroll
    for (int di = 0; di < 3; di++) {
      int hh = h + di - 1;
      if (hh < 0 || hh >= 512) continue;
      const float* rp = xc + (size_t)hh * 512 + w0;
      float xl = wl_ok ? rp[-1] : 0.f;
      float2 xm = *reinterpret_cast<const float2*>(rp);
      float xr = wr_ok ? rp[2] : 0.f;
      float wa = wv[di * 3 + 0], wb_ = wv[di * 3 + 1], wc = wv[di * 3 + 2];
      fly0 = fmaf(xl,   wa, fly0); fly0 = fmaf(xm.x, wb_, fly0); fly0 = fmaf(xm.y, wc, fly0);
      fly1 = fmaf(xm.x, wa, fly1); fly1 = fmaf(xm.y, wb_, fly1); fly1 = fmaf(xr,   wc, fly1);
    }
    const float* prow = pwt + c * 32;
#pragma unroll
    for (int o = 0; o < 32; o++) {
      float pw = prow[o];
      acc[o].x = fmaf(fly0, pw, acc[o].x);
      acc[o].y = fmaf(fly1, pw, acc[o].y);
    }
  }
  float* ob = out + (size_t)b * 32 * 262144 + (size_t)h * 512 + w0;
#pragma unroll
  for (int o = 0; o < 32; o++)
    *reinterpret_cast<float2*>(ob + (size_t)o * 262144) = acc[o];
}

extern "C" void kernel_launch(void* const* d_in, const int* in_sizes, int n_in,
                              void* d_out, int out_size, void* d_ws, size_t ws_size,
                              hipStream_t stream) {
  const float* x     = (const float*)d_in[0];
  const float* pa_w  = (const float*)d_in[1];
  const float* pa_b  = (const float*)d_in[2];
  const float* exp_w = (const float*)d_in[3];
  const float* exp_b = (const float*)d_in[4];
  const float* pw_w  = (const float*)d_in[5];
  const float* pw_b  = (const float*)d_in[6];
  float* out = (float*)d_out;
  float* ws  = (float*)d_ws;

  float* feat0p = ws;                    // 4*32*130*136 = 2,263,040
  float* tmpAp  = feat0p + 2263040;      // 2,263,040
  float* feat1p = tmpAp + 2263040;       // 4*32*66*72 = 608,256
  float* wmap   = feat1p + 608256;       // 5,242,880
  float* tmpBp  = wmap;                  // aliases wmap (dead before expander writes)
  float* wt     = wmap + 5242880;        // 73,728
  float* ewt    = wt + 73728;            // 10,240
  float* pwt    = ewt + 10240;           // 1,024

  hipLaunchKernelGGL(zero_kernel, dim3(5608), dim3(256), 0, stream, ws);
  hipLaunchKernelGGL(prep_kernel, dim3(332), dim3(256), 0, stream, pa_w, exp_w, pw_w, wt, ewt, pwt);
  hipLaunchKernelGGL(avgpool4_kernel, dim3(8192), dim3(256), 0, stream, x, feat0p);

  // predictors @128: 2-vert-px, NCO=4 -> 4b * 32 tiles * 8 groups = 1024 blocks
  for (int i = 0; i < 2; i++) {
    const float* w1 = wt + (size_t)(i * 2 + 0) * 9216;
    const float* b1 = pa_b + (i * 2 + 0) * 32;
    const float* w2 = wt + (size_t)(i * 2 + 1) * 9216;
    const float* b2 = pa_b + (i * 2 + 1) * 32;
    hipLaunchKernelGGL((conv3x3v_kernel<128, SP128, CS128, 4, true, false>),
                       dim3(1024), dim3(256), 0, stream, feat0p, w1, b1, nullptr, tmpAp);
    hipLaunchKernelGGL((conv3x3v_kernel<128, SP128, CS128, 4, false, true>),
                       dim3(1024), dim3(256), 0, stream, tmpAp, w2, b2, feat0p, feat0p);
  }

  hipLaunchKernelGGL(avgpool2_kernel, dim3(2048), dim3(256), 0, stream, feat0p, feat1p);

  // predictors @64: NCO=2 -> 1024 blocks
  for (int i = 2; i < 4; i++) {
    const float* w1 = wt + (size_t)(i * 2 + 0) * 9216;
    const float* b1 = pa_b + (i * 2 + 0) * 32;
    const float* w2 = wt + (size_t)(i * 2 + 1) * 9216;
    const float* b2 = pa_b + (i * 2 + 1) * 32;
    hipLaunchKernelGGL((conv3x3d_kernel<64, SP64, CS64, 2, true, false>),
                       dim3(1024), dim3(256), 0, stream, feat1p, w1, b1, nullptr, tmpBp);
    hipLaunchKernelGGL((conv3x3d_kernel<64, SP64, CS64, 2, false, true>),
                       dim3(1024), dim3(256), 0, stream, tmpBp, w2, b2, feat1p, feat1p);
  }

  hipLaunchKernelGGL(expander_kernel, dim3(5120), dim3(256), 0, stream, feat1p, ewt, exp_b, wmap);

  hipLaunchKernelGGL(fused_fly_pw_kernel, dim3(2048), dim3(256), 0, stream,
                     x, wmap, pwt, pw_b, out);
}